// Round 1
// baseline (322.525 us; speedup 1.0000x reference)
//
#include <hip/hip_runtime.h>
#include <math.h>

// Problem constants (B,N,M,F,K) = (32,256,64,128,64)
#define PB 32
#define PN 256
#define PM 64
#define PF 128
#define PK 64
#define ROWS (PB*PN)          // 8192 atom rows
#define NTOT (ROWS*PF)        // 1048576

// bf16 weight arena offsets (elements)
#define OFF_K2F  0
#define OFF_WI   8192
#define OFF_IW1  24576
#define OFF_IW2  73728
#define OFF_WINT 122880
#define OFF_AW1  139264
#define OFF_AW2  172032
#define TOTAL_W  204800

#define XPITCH 136            // LDS row pitch (ushorts)

typedef __attribute__((ext_vector_type(4))) float  floatx4;
typedef __attribute__((ext_vector_type(8))) short  shortx8;

__device__ __forceinline__ unsigned short f2b(float f){
    union { float f; unsigned int i; } c; c.f = f;
    unsigned int x = c.i;
    return (unsigned short)((x + 0x7fffu + ((x >> 16) & 1u)) >> 16);
}
__device__ __forceinline__ float bf2f(unsigned short u){
    union { unsigned int i; float f; } c; c.i = ((unsigned int)u) << 16; return c.f;
}
__device__ __forceinline__ float sspf(float x){
    return fmaxf(x, 0.0f) + log1pf(expf(-fabsf(x))) - 0.69314718055994531f;
}
__device__ __forceinline__ shortx8 pack8(float4 a, float4 b){
    shortx8 r;
    r[0]=(short)f2b(a.x); r[1]=(short)f2b(a.y); r[2]=(short)f2b(a.z); r[3]=(short)f2b(a.w);
    r[4]=(short)f2b(b.x); r[5]=(short)f2b(b.y); r[6]=(short)f2b(b.z); r[7]=(short)f2b(b.w);
    return r;
}

// ---- kernel 1: xa_f = ssp(x) fp32; xa_b = bf16(ssp(x)); weights -> bf16 arena ----
__global__ __launch_bounds__(256) void k_pre(const float* __restrict__ x,
                                             const float* __restrict__ k2f,
                                             const float* __restrict__ Wi,
                                             const float* __restrict__ iW1,
                                             const float* __restrict__ iW2,
                                             const float* __restrict__ Wint,
                                             const float* __restrict__ aW1,
                                             const float* __restrict__ aW2,
                                             float* __restrict__ xa_f,
                                             unsigned short* __restrict__ xa_b,
                                             unsigned short* __restrict__ Wb){
    int i = blockIdx.x * 256 + threadIdx.x;
    if (i < NTOT){
        float v = sspf(x[i]);
        xa_f[i] = v;
        xa_b[i] = f2b(v);
        return;
    }
    int j = i - NTOT;
    if (j >= TOTAL_W) return;
    float v;
    if      (j < OFF_WI)   v = k2f[j - OFF_K2F];
    else if (j < OFF_IW1)  v = Wi[j - OFF_WI];
    else if (j < OFF_IW2)  v = iW1[j - OFF_IW1];
    else if (j < OFF_WINT) v = iW2[j - OFF_IW2];
    else if (j < OFF_AW1)  v = Wint[j - OFF_WINT];
    else if (j < OFF_AW2)  v = aW1[j - OFF_AW1];
    else                   v = aW2[j - OFF_AW2];
    Wb[j] = f2b(v);
}

// ---------------- kernel 2: message aggregation, WAVE-PER-M-TILE ----------------
// Block = 1 atom, 4 waves; wave t handles m-rows [16t, 16t+16).
// All of a wave's rbf bytes (4 x float4/lane) issue up-front -> Little's-law
// outstanding bytes go 4x per wave AND wave count goes 4x (32768 waves).
// Cross-wave (m) reduction via 2KB LDS + one barrier.
__global__ __launch_bounds__(256) void k_msg(const float* __restrict__ rbf,
                                             const int* __restrict__ nbr,
                                             const unsigned short* __restrict__ Wk2f, // bf16
                                             const float* __restrict__ xa_f,
                                             float* __restrict__ xj){
    const int tid  = threadIdx.x;
    const int t    = tid >> 6;            // wave id = m-tile index
    const int bid  = blockIdx.x;          // atom id = b*256+n
    const int b    = bid >> 8;
    const int lane = tid & 63;
    const int quad = lane >> 4;
    const int l16  = lane & 15;

    __shared__ float red[4][PF];          // 2 KB

    // ---- issue ALL global loads before any dependent compute ----
    const float* rrow = rbf + (size_t)bid * (PM*PK) + (size_t)(t*16 + l16) * PK;
    float4 r0 = *(const float4*)(rrow + quad*8);
    float4 r1 = *(const float4*)(rrow + quad*8 + 4);
    float4 r2 = *(const float4*)(rrow + 32 + quad*8);
    float4 r3 = *(const float4*)(rrow + 32 + quad*8 + 4);
    // neighbor rows this lane's quad owns in the MFMA C-layout (m = t*16+quad*4+r)
    int4 nb = *(const int4*)(nbr + (size_t)bid*PM + t*16 + quad*4);

    const float* xab = xa_f + (size_t)b * PN * PF;

    // A fragments: A[m=l16][k=quad*8+j] (k 0..31) and (k 32..63)
    shortx8 afrag0 = pack8(r0, r1);
    shortx8 afrag1 = pack8(r2, r3);

    float s[8];
    #pragma unroll
    for (int ft = 0; ft < 8; ++ft){
        const unsigned short* wrow = Wk2f + (size_t)(ft*16 + l16) * PK;
        shortx8 b0 = *(const shortx8*)(wrow +  0 + quad*8);
        shortx8 b1 = *(const shortx8*)(wrow + 32 + quad*8);
        floatx4 acc = {0.f, 0.f, 0.f, 0.f};
        acc = __builtin_amdgcn_mfma_f32_16x16x32_bf16(afrag0, b0, acc, 0, 0, 0);
        acc = __builtin_amdgcn_mfma_f32_16x16x32_bf16(afrag1, b1, acc, 0, 0, 0);
        const int col = ft*16 + l16;
        float v =  acc[0] * xab[(size_t)nb.x*PF + col];
        v       += acc[1] * xab[(size_t)nb.y*PF + col];
        v       += acc[2] * xab[(size_t)nb.z*PF + col];
        v       += acc[3] * xab[(size_t)nb.w*PF + col];
        s[ft] = v;
    }

    // reduce over the 4 quads (m within tile), stash per-wave partial in LDS
    #pragma unroll
    for (int ft = 0; ft < 8; ++ft){
        float v = s[ft];
        v += __shfl_xor(v, 16, 64);
        v += __shfl_xor(v, 32, 64);
        if (quad == 0) red[t][ft*16 + l16] = v;
    }
    __syncthreads();
    // sum the 4 m-tiles
    if (tid < PF){
        xj[(size_t)bid*PF + tid] = red[0][tid] + red[1][tid] + red[2][tid] + red[3][tid];
    }
}

// ---------------- kernel 3: fused 12-stage chain (double-buffered LDS) ----------------
__device__ __forceinline__ void gemm2(const unsigned short* __restrict__ W,
                                      int l16, int quad, int ftbase,
                                      const shortx8 a[4], floatx4 acc[2]){
    #pragma unroll
    for (int f = 0; f < 2; ++f){
        const unsigned short* wrow = W + (size_t)((ftbase+f)*16 + l16) * PF;
        floatx4 c = {0.f, 0.f, 0.f, 0.f};
        #pragma unroll
        for (int ks = 0; ks < 4; ++ks){
            shortx8 bf = *(const shortx8*)(wrow + ks*32 + quad*8);
            c = __builtin_amdgcn_mfma_f32_16x16x32_bf16(a[ks], bf, c, 0, 0, 0);
        }
        acc[f] = c;
    }
}

// write C-layout t16 into buffer p, barrier once, read back A-frags
__device__ __forceinline__ void relayout(unsigned short* Tls,   // base of buffer p
                                         const unsigned short t16[8],
                                         int l16, int quad, int ftbase,
                                         shortx8 a[4]){
    #pragma unroll
    for (int f = 0; f < 2; ++f)
        #pragma unroll
        for (int r = 0; r < 4; ++r)
            Tls[(quad*4 + r)*XPITCH + (ftbase+f)*16 + l16] = t16[f*4 + r];
    __syncthreads();   // RAW; WAR across stages handled by double-buffering
    #pragma unroll
    for (int ks = 0; ks < 4; ++ks)
        a[ks] = *(const shortx8*)(Tls + l16*XPITCH + ks*32 + quad*8);
}

__global__ __launch_bounds__(256) void k_chain(const unsigned short* __restrict__ xa_b,
                                               const float* __restrict__ xj,
                                               const float* __restrict__ x,
                                               const unsigned short* __restrict__ Wb,
                                               const float* __restrict__ bi,
                                               const float* __restrict__ ib1,
                                               const float* __restrict__ ib2,
                                               const float* __restrict__ bint,
                                               const float* __restrict__ ugate,
                                               const float* __restrict__ ab1,
                                               const float* __restrict__ ab2,
                                               float* __restrict__ out){
    const int tid  = threadIdx.x;
    const int wave = tid >> 6;
    const int lane = tid & 63;
    const int quad = lane >> 4;
    const int l16  = lane & 15;
    const int ftb  = wave*2;
    const int row0 = blockIdx.x * 16;

    __shared__ unsigned short Tls[2][16 * XPITCH];   // 8.5 KB double buffer
    int p = 0;

    int col[2];
    #pragma unroll
    for (int f = 0; f < 2; ++f) col[f] = (ftb+f)*16 + l16;

    const unsigned short* inrow = xa_b + (size_t)(row0 + l16) * PF;
    shortx8 a[4];
    #pragma unroll
    for (int ks = 0; ks < 4; ++ks)
        a[ks] = *(const shortx8*)(inrow + ks*32 + quad*8);

    floatx4 acc[2];
    float V[8];
    unsigned short t16[8];

    // ---- stage A: v = ssp(xa@Wi^T + bi) + xj ----
    gemm2(Wb + OFF_WI, l16, quad, ftb, a, acc);
    #pragma unroll
    for (int f = 0; f < 2; ++f)
        #pragma unroll
        for (int r = 0; r < 4; ++r){
            size_t idx = (size_t)(row0 + quad*4 + r)*PF + col[f];
            float of = sspf(acc[f][r] + bi[col[f]]) + xj[idx];
            V[f*4+r] = of;
            t16[f*4+r] = f2b(sspf(of));
        }
    relayout(Tls[p], t16, l16, quad, ftb, a); p ^= 1;

    // ---- 3 interaction residual blocks ----
    for (int l = 0; l < 3; ++l){
        gemm2(Wb + OFF_IW1 + l*PF*PF, l16, quad, ftb, a, acc);
        #pragma unroll
        for (int f = 0; f < 2; ++f)
            #pragma unroll
            for (int r = 0; r < 4; ++r)
                t16[f*4+r] = f2b(sspf(acc[f][r] + ib1[l*PF + col[f]]));
        relayout(Tls[p], t16, l16, quad, ftb, a); p ^= 1;

        gemm2(Wb + OFF_IW2 + l*PF*PF, l16, quad, ftb, a, acc);
        #pragma unroll
        for (int f = 0; f < 2; ++f)
            #pragma unroll
            for (int r = 0; r < 4; ++r){
                V[f*4+r] += acc[f][r] + ib2[l*PF + col[f]];
                t16[f*4+r] = f2b(sspf(V[f*4+r]));
            }
        relayout(Tls[p], t16, l16, quad, ftb, a); p ^= 1;
    }

    // ---- gate: out = u_gate*x + ssp(v)@Wint^T + bint ----
    gemm2(Wb + OFF_WINT, l16, quad, ftb, a, acc);
    #pragma unroll
    for (int f = 0; f < 2; ++f)
        #pragma unroll
        for (int r = 0; r < 4; ++r){
            size_t idx = (size_t)(row0 + quad*4 + r)*PF + col[f];
            float o = ugate[col[f]] * x[idx] + acc[f][r] + bint[col[f]];
            V[f*4+r] = o;
            t16[f*4+r] = f2b(sspf(o));
        }
    relayout(Tls[p], t16, l16, quad, ftb, a); p ^= 1;

    // ---- 2 atom residual blocks ----
    #pragma unroll
    for (int l = 0; l < 2; ++l){
        gemm2(Wb + OFF_AW1 + l*PF*PF, l16, quad, ftb, a, acc);
        #pragma unroll
        for (int f = 0; f < 2; ++f)
            #pragma unroll
            for (int r = 0; r < 4; ++r)
                t16[f*4+r] = f2b(sspf(acc[f][r] + ab1[l*PF + col[f]]));
        relayout(Tls[p], t16, l16, quad, ftb, a); p ^= 1;

        gemm2(Wb + OFF_AW2 + l*PF*PF, l16, quad, ftb, a, acc);
        if (l == 0){
            #pragma unroll
            for (int f = 0; f < 2; ++f)
                #pragma unroll
                for (int r = 0; r < 4; ++r){
                    V[f*4+r] += acc[f][r] + ab2[l*PF + col[f]];
                    t16[f*4+r] = f2b(sspf(V[f*4+r]));
                }
            relayout(Tls[p], t16, l16, quad, ftb, a); p ^= 1;
        } else {
            #pragma unroll
            for (int f = 0; f < 2; ++f)
                #pragma unroll
                for (int r = 0; r < 4; ++r){
                    size_t idx = (size_t)(row0 + quad*4 + r)*PF + col[f];
                    out[idx] = V[f*4+r] + acc[f][r] + ab2[l*PF + col[f]];
                }
        }
    }
}

extern "C" void kernel_launch(void* const* d_in, const int* in_sizes, int n_in,
                              void* d_out, int out_size, void* d_ws, size_t ws_size,
                              hipStream_t stream){
    const float* x     = (const float*)d_in[0];
    const float* rbf   = (const float*)d_in[1];
    const int*   nbr   = (const int*)d_in[2];
    const float* k2fW  = (const float*)d_in[3];
    const float* Wi    = (const float*)d_in[4];
    const float* bi    = (const float*)d_in[5];
    const float* iW1   = (const float*)d_in[6];
    const float* ib1   = (const float*)d_in[7];
    const float* iW2   = (const float*)d_in[8];
    const float* ib2   = (const float*)d_in[9];
    const float* Wint  = (const float*)d_in[10];
    const float* bint  = (const float*)d_in[11];
    const float* ugate = (const float*)d_in[12];
    const float* aW1   = (const float*)d_in[13];
    const float* ab1   = (const float*)d_in[14];
    const float* aW2   = (const float*)d_in[15];
    const float* ab2   = (const float*)d_in[16];

    // Workspace (~10.4 MB):
    //   xa_b [0,2MB) bf16 ; xa_f [2,6MB) fp32 ; xj [6,10MB) fp32 ; Wb [10MB,+400K)
    char* ws = (char*)d_ws;
    unsigned short* xa_b = (unsigned short*)ws;
    float*          xa_f = (float*)(ws + (2ull  << 20));
    float*          xj   = (float*)(ws + (6ull  << 20));
    unsigned short* Wb   = (unsigned short*)(ws + (10ull << 20));

    k_pre<<<(NTOT + TOTAL_W + 255)/256, 256, 0, stream>>>(
        x, k2fW, Wi, iW1, iW2, Wint, aW1, aW2, xa_f, xa_b, Wb);
    k_msg<<<ROWS, 256, 0, stream>>>(rbf, nbr, Wb + OFF_K2F, xa_f, xj);
    k_chain<<<ROWS/16, 256, 0, stream>>>(xa_b, xj, x, Wb,
                                         bi, ib1, ib2, bint, ugate, ab1, ab2,
                                         (float*)d_out);
}

// Round 2
// 288.102 us; speedup vs baseline: 1.1195x; 1.1195x over previous
//
#include <hip/hip_runtime.h>
#include <math.h>

// Problem constants (B,N,M,F,K) = (32,256,64,128,64)
#define PB 32
#define PN 256
#define PM 64
#define PF 128
#define PK 64
#define ROWS (PB*PN)          // 8192 atom rows
#define NTOT (ROWS*PF)        // 1048576

// bf16 weight arena offsets (elements)
#define OFF_K2F  0
#define OFF_WI   8192
#define OFF_IW1  24576
#define OFF_IW2  73728
#define OFF_WINT 122880
#define OFF_AW1  139264
#define OFF_AW2  172032
#define TOTAL_W  204800

#define XPITCH 136            // LDS row pitch (ushorts) for k_chain

#define APB 32                // atoms per k_msg block (256 blocks = 1/CU)

typedef __attribute__((ext_vector_type(4))) float  floatx4;
typedef __attribute__((ext_vector_type(8))) short  shortx8;

__device__ __forceinline__ unsigned short f2b(float f){
    union { float f; unsigned int i; } c; c.f = f;
    unsigned int x = c.i;
    return (unsigned short)((x + 0x7fffu + ((x >> 16) & 1u)) >> 16);
}
__device__ __forceinline__ float bf2f(unsigned short u){
    union { unsigned int i; float f; } c; c.i = ((unsigned int)u) << 16; return c.f;
}
__device__ __forceinline__ float sspf(float x){
    return fmaxf(x, 0.0f) + log1pf(expf(-fabsf(x))) - 0.69314718055994531f;
}
__device__ __forceinline__ shortx8 pack8(float4 a, float4 b){
    shortx8 r;
    r[0]=(short)f2b(a.x); r[1]=(short)f2b(a.y); r[2]=(short)f2b(a.z); r[3]=(short)f2b(a.w);
    r[4]=(short)f2b(b.x); r[5]=(short)f2b(b.y); r[6]=(short)f2b(b.z); r[7]=(short)f2b(b.w);
    return r;
}

// ---- kernel 1: xa_f = ssp(x) fp32; xa_b = bf16(ssp(x)); weights -> bf16 arena ----
__global__ __launch_bounds__(256) void k_pre(const float* __restrict__ x,
                                             const float* __restrict__ k2f,
                                             const float* __restrict__ Wi,
                                             const float* __restrict__ iW1,
                                             const float* __restrict__ iW2,
                                             const float* __restrict__ Wint,
                                             const float* __restrict__ aW1,
                                             const float* __restrict__ aW2,
                                             float* __restrict__ xa_f,
                                             unsigned short* __restrict__ xa_b,
                                             unsigned short* __restrict__ Wb){
    int i = blockIdx.x * 256 + threadIdx.x;
    if (i < NTOT){
        float v = sspf(x[i]);
        xa_f[i] = v;
        xa_b[i] = f2b(v);
        return;
    }
    int j = i - NTOT;
    if (j >= TOTAL_W) return;
    float v;
    if      (j < OFF_WI)   v = k2f[j - OFF_K2F];
    else if (j < OFF_IW1)  v = Wi[j - OFF_WI];
    else if (j < OFF_IW2)  v = iW1[j - OFF_IW1];
    else if (j < OFF_WINT) v = iW2[j - OFF_IW2];
    else if (j < OFF_AW1)  v = Wint[j - OFF_WINT];
    else if (j < OFF_AW2)  v = aW1[j - OFF_AW1];
    else                   v = aW2[j - OFF_AW2];
    Wb[j] = f2b(v);
}

// ---------------- kernel 2: message aggregation, batch-staged LDS gather ----------------
// Block = 512 threads (8 waves) = 2 atom-slots x 4 m-tiles, handles 32 atoms of ONE
// batch image. The batch's xa (fp32, 128 KB) is staged in LDS once; neighbor gathers
// become ds_read (latency-insensitive). rbf is the only HBM stream, prefetched one
// atom ahead per wave, so vmcnt waits only at the HBM roof. B-fragments (k2f weights)
// are hoisted into registers. 256 blocks = exactly 1 resident block per CU (136 KB LDS).
__global__ __launch_bounds__(512) void k_msg(const float* __restrict__ rbf,
                                             const int* __restrict__ nbr,
                                             const unsigned short* __restrict__ Wk2f, // bf16
                                             const float* __restrict__ xa_f,
                                             float* __restrict__ xj){
    const int tid  = threadIdx.x;
    const int w    = tid >> 6;        // wave 0..7
    const int lane = tid & 63;
    const int quad = lane >> 4;
    const int l16  = lane & 15;
    const int slot = w >> 2;          // 0,1 : which atom parity this wave serves
    const int t    = w & 3;           // m-tile 0..3

    const int blk   = blockIdx.x;     // 0..255
    const int b     = blk >> 3;       // batch image
    const int n0    = (blk & 7) * APB;
    const int atom0 = b * PN + n0;    // global atom id base

    __shared__ float xa_s[PN * PF];        // 128 KB: whole batch image, fp32
    __shared__ float red[2][2][4][PF];     // 8 KB: [parity][slot][tile][col]

    // ---- issue first atom's rbf + nbr loads (in flight during staging) ----
    const int rowoff = (t*16 + l16) * PK + quad*8;
    {
    }
    const float* rb0 = rbf + (size_t)(atom0 + slot) * (PM*PK) + rowoff;
    float4 r0 = *(const float4*)(rb0);
    float4 r1 = *(const float4*)(rb0 + 4);
    float4 r2 = *(const float4*)(rb0 + 32);
    float4 r3 = *(const float4*)(rb0 + 36);
    int4  nb  = *(const int4*)(nbr + (size_t)(atom0 + slot)*PM + t*16 + quad*4);

    // ---- stage batch xa image into LDS (coalesced float4 copy, 128 KB) ----
    const float* src = xa_f + (size_t)b * (PN*PF);
    #pragma unroll
    for (int p = 0; p < 16; ++p){
        int idx = p*2048 + tid*4;
        *(float4*)(&xa_s[idx]) = *(const float4*)(src + idx);
    }

    // ---- hoist B fragments (k2f weights, 16 KB hot) into registers ----
    shortx8 bf0[8], bf1[8];
    #pragma unroll
    for (int ft = 0; ft < 8; ++ft){
        const unsigned short* wrow = Wk2f + (size_t)(ft*16 + l16) * PK;
        bf0[ft] = *(const shortx8*)(wrow + quad*8);
        bf1[ft] = *(const shortx8*)(wrow + 32 + quad*8);
    }

    __syncthreads();   // xa_s ready (also drains the first rbf loads)

    for (int it = 0; it < APB/2; ++it){
        const int a = slot + it*2;               // atom index within block

        shortx8 af0 = pack8(r0, r1);
        shortx8 af1 = pack8(r2, r3);
        const int j0 = nb.x, j1 = nb.y, j2 = nb.z, j3 = nb.w;

        // prefetch next atom for this slot (one deep; arrival hidden by ~1 iter)
        if (it + 1 < APB/2){
            const float* rbn = rbf + (size_t)(atom0 + a + 2) * (PM*PK) + rowoff;
            r0 = *(const float4*)(rbn);
            r1 = *(const float4*)(rbn + 4);
            r2 = *(const float4*)(rbn + 32);
            r3 = *(const float4*)(rbn + 36);
            nb = *(const int4*)(nbr + (size_t)(atom0 + a + 2)*PM + t*16 + quad*4);
        }

        // 16 MFMA: G-tile for this wave's 16 m-rows, all 128 features
        floatx4 acc8[8];
        #pragma unroll
        for (int ft = 0; ft < 8; ++ft){
            floatx4 c = {0.f, 0.f, 0.f, 0.f};
            c = __builtin_amdgcn_mfma_f32_16x16x32_bf16(af0, bf0[ft], c, 0, 0, 0);
            c = __builtin_amdgcn_mfma_f32_16x16x32_bf16(af1, bf1[ft], c, 0, 0, 0);
            acc8[ft] = c;
        }

        // gather-from-LDS, fp32 (same numerics as before); per-row bases with
        // constant offsets so the compiler can merge into ds_read2_b32
        const float* rp0 = xa_s + (size_t)j0*PF + l16;
        const float* rp1 = xa_s + (size_t)j1*PF + l16;
        const float* rp2 = xa_s + (size_t)j2*PF + l16;
        const float* rp3 = xa_s + (size_t)j3*PF + l16;
        float s[8];
        #pragma unroll
        for (int ft = 0; ft < 8; ++ft){
            float v =  acc8[ft][0] * rp0[ft*16];
            v       += acc8[ft][1] * rp1[ft*16];
            v       += acc8[ft][2] * rp2[ft*16];
            v       += acc8[ft][3] * rp3[ft*16];
            s[ft] = v;
        }

        // reduce over the 4 quads (m within tile), stash per-tile partial
        #pragma unroll
        for (int ft = 0; ft < 8; ++ft){
            float v = s[ft];
            v += __shfl_xor(v, 16, 64);
            v += __shfl_xor(v, 32, 64);
            if (quad == 0) red[it & 1][slot][t][ft*16 + l16] = v;
        }
        __syncthreads();

        // wave t==0 of each slot sums the 4 m-tiles and stores xj for atom a
        if (t == 0){
            const float* rd = &red[it & 1][slot][0][0];
            float2 v0 = *(const float2*)(rd + 0*PF + 2*lane);
            float2 v1 = *(const float2*)(rd + 1*PF + 2*lane);
            float2 v2 = *(const float2*)(rd + 2*PF + 2*lane);
            float2 v3 = *(const float2*)(rd + 3*PF + 2*lane);
            float2 o;
            o.x = v0.x + v1.x + v2.x + v3.x;
            o.y = v0.y + v1.y + v2.y + v3.y;
            *(float2*)(xj + (size_t)(atom0 + a)*PF + 2*lane) = o;
        }
        // no extra barrier needed: next iteration writes red[parity^1]; the
        // following reuse of this parity is preceded by the next barrier.
    }
}

// ---------------- kernel 3: fused 12-stage chain (double-buffered LDS) ----------------
__device__ __forceinline__ void gemm2(const unsigned short* __restrict__ W,
                                      int l16, int quad, int ftbase,
                                      const shortx8 a[4], floatx4 acc[2]){
    #pragma unroll
    for (int f = 0; f < 2; ++f){
        const unsigned short* wrow = W + (size_t)((ftbase+f)*16 + l16) * PF;
        floatx4 c = {0.f, 0.f, 0.f, 0.f};
        #pragma unroll
        for (int ks = 0; ks < 4; ++ks){
            shortx8 bf = *(const shortx8*)(wrow + ks*32 + quad*8);
            c = __builtin_amdgcn_mfma_f32_16x16x32_bf16(a[ks], bf, c, 0, 0, 0);
        }
        acc[f] = c;
    }
}

// write C-layout t16 into buffer p, barrier once, read back A-frags
__device__ __forceinline__ void relayout(unsigned short* Tls,   // base of buffer p
                                         const unsigned short t16[8],
                                         int l16, int quad, int ftbase,
                                         shortx8 a[4]){
    #pragma unroll
    for (int f = 0; f < 2; ++f)
        #pragma unroll
        for (int r = 0; r < 4; ++r)
            Tls[(quad*4 + r)*XPITCH + (ftbase+f)*16 + l16] = t16[f*4 + r];
    __syncthreads();   // RAW; WAR across stages handled by double-buffering
    #pragma unroll
    for (int ks = 0; ks < 4; ++ks)
        a[ks] = *(const shortx8*)(Tls + l16*XPITCH + ks*32 + quad*8);
}

__global__ __launch_bounds__(256) void k_chain(const unsigned short* __restrict__ xa_b,
                                               const float* __restrict__ xj,
                                               const float* __restrict__ x,
                                               const unsigned short* __restrict__ Wb,
                                               const float* __restrict__ bi,
                                               const float* __restrict__ ib1,
                                               const float* __restrict__ ib2,
                                               const float* __restrict__ bint,
                                               const float* __restrict__ ugate,
                                               const float* __restrict__ ab1,
                                               const float* __restrict__ ab2,
                                               float* __restrict__ out){
    const int tid  = threadIdx.x;
    const int wave = tid >> 6;
    const int lane = tid & 63;
    const int quad = lane >> 4;
    const int l16  = lane & 15;
    const int ftb  = wave*2;
    const int row0 = blockIdx.x * 16;

    __shared__ unsigned short Tls[2][16 * XPITCH];   // 8.5 KB double buffer
    int p = 0;

    int col[2];
    #pragma unroll
    for (int f = 0; f < 2; ++f) col[f] = (ftb+f)*16 + l16;

    const unsigned short* inrow = xa_b + (size_t)(row0 + l16) * PF;
    shortx8 a[4];
    #pragma unroll
    for (int ks = 0; ks < 4; ++ks)
        a[ks] = *(const shortx8*)(inrow + ks*32 + quad*8);

    floatx4 acc[2];
    float V[8];
    unsigned short t16[8];

    // ---- stage A: v = ssp(xa@Wi^T + bi) + xj ----
    gemm2(Wb + OFF_WI, l16, quad, ftb, a, acc);
    #pragma unroll
    for (int f = 0; f < 2; ++f)
        #pragma unroll
        for (int r = 0; r < 4; ++r){
            size_t idx = (size_t)(row0 + quad*4 + r)*PF + col[f];
            float of = sspf(acc[f][r] + bi[col[f]]) + xj[idx];
            V[f*4+r] = of;
            t16[f*4+r] = f2b(sspf(of));
        }
    relayout(Tls[p], t16, l16, quad, ftb, a); p ^= 1;

    // ---- 3 interaction residual blocks ----
    for (int l = 0; l < 3; ++l){
        gemm2(Wb + OFF_IW1 + l*PF*PF, l16, quad, ftb, a, acc);
        #pragma unroll
        for (int f = 0; f < 2; ++f)
            #pragma unroll
            for (int r = 0; r < 4; ++r)
                t16[f*4+r] = f2b(sspf(acc[f][r] + ib1[l*PF + col[f]]));
        relayout(Tls[p], t16, l16, quad, ftb, a); p ^= 1;

        gemm2(Wb + OFF_IW2 + l*PF*PF, l16, quad, ftb, a, acc);
        #pragma unroll
        for (int f = 0; f < 2; ++f)
            #pragma unroll
            for (int r = 0; r < 4; ++r){
                V[f*4+r] += acc[f][r] + ib2[l*PF + col[f]];
                t16[f*4+r] = f2b(sspf(V[f*4+r]));
            }
        relayout(Tls[p], t16, l16, quad, ftb, a); p ^= 1;
    }

    // ---- gate: out = u_gate*x + ssp(v)@Wint^T + bint ----
    gemm2(Wb + OFF_WINT, l16, quad, ftb, a, acc);
    #pragma unroll
    for (int f = 0; f < 2; ++f)
        #pragma unroll
        for (int r = 0; r < 4; ++r){
            size_t idx = (size_t)(row0 + quad*4 + r)*PF + col[f];
            float o = ugate[col[f]] * x[idx] + acc[f][r] + bint[col[f]];
            V[f*4+r] = o;
            t16[f*4+r] = f2b(sspf(o));
        }
    relayout(Tls[p], t16, l16, quad, ftb, a); p ^= 1;

    // ---- 2 atom residual blocks ----
    #pragma unroll
    for (int l = 0; l < 2; ++l){
        gemm2(Wb + OFF_AW1 + l*PF*PF, l16, quad, ftb, a, acc);
        #pragma unroll
        for (int f = 0; f < 2; ++f)
            #pragma unroll
            for (int r = 0; r < 4; ++r)
                t16[f*4+r] = f2b(sspf(acc[f][r] + ab1[l*PF + col[f]]));
        relayout(Tls[p], t16, l16, quad, ftb, a); p ^= 1;

        gemm2(Wb + OFF_AW2 + l*PF*PF, l16, quad, ftb, a, acc);
        if (l == 0){
            #pragma unroll
            for (int f = 0; f < 2; ++f)
                #pragma unroll
                for (int r = 0; r < 4; ++r){
                    V[f*4+r] += acc[f][r] + ab2[l*PF + col[f]];
                    t16[f*4+r] = f2b(sspf(V[f*4+r]));
                }
            relayout(Tls[p], t16, l16, quad, ftb, a); p ^= 1;
        } else {
            #pragma unroll
            for (int f = 0; f < 2; ++f)
                #pragma unroll
                for (int r = 0; r < 4; ++r){
                    size_t idx = (size_t)(row0 + quad*4 + r)*PF + col[f];
                    out[idx] = V[f*4+r] + acc[f][r] + ab2[l*PF + col[f]];
                }
        }
    }
}

extern "C" void kernel_launch(void* const* d_in, const int* in_sizes, int n_in,
                              void* d_out, int out_size, void* d_ws, size_t ws_size,
                              hipStream_t stream){
    const float* x     = (const float*)d_in[0];
    const float* rbf   = (const float*)d_in[1];
    const int*   nbr   = (const int*)d_in[2];
    const float* k2fW  = (const float*)d_in[3];
    const float* Wi    = (const float*)d_in[4];
    const float* bi    = (const float*)d_in[5];
    const float* iW1   = (const float*)d_in[6];
    const float* ib1   = (const float*)d_in[7];
    const float* iW2   = (const float*)d_in[8];
    const float* ib2   = (const float*)d_in[9];
    const float* Wint  = (const float*)d_in[10];
    const float* bint  = (const float*)d_in[11];
    const float* ugate = (const float*)d_in[12];
    const float* aW1   = (const float*)d_in[13];
    const float* ab1   = (const float*)d_in[14];
    const float* aW2   = (const float*)d_in[15];
    const float* ab2   = (const float*)d_in[16];

    // Workspace (~10.4 MB):
    //   xa_b [0,2MB) bf16 ; xa_f [2,6MB) fp32 ; xj [6,10MB) fp32 ; Wb [10MB,+400K)
    char* ws = (char*)d_ws;
    unsigned short* xa_b = (unsigned short*)ws;
    float*          xa_f = (float*)(ws + (2ull  << 20));
    float*          xj   = (float*)(ws + (6ull  << 20));
    unsigned short* Wb   = (unsigned short*)(ws + (10ull << 20));

    k_pre<<<(NTOT + TOTAL_W + 255)/256, 256, 0, stream>>>(
        x, k2fW, Wi, iW1, iW2, Wint, aW1, aW2, xa_f, xa_b, Wb);
    k_msg<<<PB * (PN/APB), 512, 0, stream>>>(rbf, nbr, Wb + OFF_K2F, xa_f, xj);
    k_chain<<<ROWS/16, 256, 0, stream>>>(xa_b, xj, x, Wb,
                                         bi, ib1, ib2, bint, ugate, ab1, ab2,
                                         (float*)d_out);
}